// Round 10
// baseline (686.927 us; speedup 1.0000x reference)
//
#include <hip/hip_runtime.h>
#include <hip/hip_bf16.h>
#include <hip/hip_fp8.h>

#define LL 128
#define BB 32
#define EE 128
#define HH 256
#define NHH 8
#define G3 768   // 3*H
#define IN0 130
#define ETA 100
#define F1 168
#define CLSIN 2304  // 8*256 + 256

typedef _Float16 half_t;
typedef __attribute__((ext_vector_type(2))) _Float16 half2v;
typedef __attribute__((ext_vector_type(4))) float floatx4;

#if defined(__has_builtin)
#if __has_builtin(__builtin_amdgcn_fdot2)
#define HAVE_FDOT2 1
#endif
#endif

__device__ __forceinline__ float fdot2f(half2v a, half2v b, float c) {
#ifdef HAVE_FDOT2
  return __builtin_amdgcn_fdot2(a, b, c, false);
#else
  return c + (float)a.x * (float)b.x + (float)a.y * (float)b.y;
#endif
}

// LDS-only barrier: no vmcnt drain — weight prefetch loads stay in flight
// across the per-step barrier (cp.async-style pipelining).
#define BARRIER_LDS() __asm__ volatile("s_waitcnt lgkmcnt(0)\n\ts_barrier" ::: "memory")

__device__ __forceinline__ float sigmoidf_(float x) { return 1.0f / (1.0f + __expf(-x)); }
__device__ __forceinline__ float tanhf_(float x) { return 1.0f - 2.0f / (__expf(2.0f * x) + 1.0f); }

// ---------------------------------------------------------------------------
// prep: weight repack. Wa0/Wih -> f16. Whh -> fp8 e4m3 (absmax 0.031 verified r8).
// ---------------------------------------------------------------------------
__global__ void prep_kernel(
    const float* __restrict__ Wa0, const float* __restrict__ Wih0,
    const float* __restrict__ Wih1, const float* __restrict__ Whh0,
    const float* __restrict__ Whh1,
    half_t* __restrict__ Wa0Ta, half_t* __restrict__ Wa0Tb,
    half2v* __restrict__ Wih0T2, half2v* __restrict__ Wih1T2,
    __hip_fp8_e4m3* __restrict__ Whh0q, __hip_fp8_e4m3* __restrict__ Whh1q)
{
  int idx = blockIdx.x * blockDim.x + threadIdx.x;
  const int n1 = 16384, n2 = 16384, n3 = 65 * 768, n4 = 128 * 768, n5 = 196608;
  if (idx < n1) {
    int d = idx >> 7, k = idx & 127;
    Wa0Ta[idx] = (half_t)Wa0[k * 256 + d];
  } else if ((idx -= n1) < n2) {
    int d = idx >> 7, k = idx & 127;
    Wa0Tb[idx] = (half_t)Wa0[k * 256 + 128 + d];
  } else if ((idx -= n2) < n3) {
    int d2 = idx / 768, r = idx % 768;
    half2v w; w.x = (half_t)Wih0[r * IN0 + 2 * d2]; w.y = (half_t)Wih0[r * IN0 + 2 * d2 + 1];
    Wih0T2[idx] = w;
  } else if ((idx -= n3) < n4) {
    int d2 = idx / 768, r = idx % 768;
    half2v w; w.x = (half_t)Wih1[r * HH + 2 * d2]; w.y = (half_t)Wih1[r * HH + 2 * d2 + 1];
    Wih1T2[idx] = w;
  } else if ((idx -= n4) < n5) {
    Whh0q[idx] = __hip_fp8_e4m3(Whh0[idx]);
  } else if ((idx -= n5) < n5) {
    Whh1q[idx] = __hip_fp8_e4m3(Whh1[idx]);
  }
}

// ---------------------------------------------------------------------------
// embed gather + U/V factors of the pairwise attention
// ---------------------------------------------------------------------------
__global__ void embed_uv_kernel(
    const int* __restrict__ node,             // [L*B]
    const float* __restrict__ table,          // [20001][128]
    const half_t* __restrict__ Wa0Ta,         // [128 d][128 k]
    const half_t* __restrict__ Wa0Tb,
    const float* __restrict__ ba0,            // [128]
    half2v* __restrict__ e_h2,                // [L*B][64]
    float* __restrict__ U,
    float* __restrict__ V)
{
  int lb = blockIdx.x;
  int k = threadIdx.x;  // 128
  __shared__ float es[EE];
  int n = node[lb];
  float ev = table[(size_t)n * EE + k];
  es[k] = ev;
  __syncthreads();
  if (k < 64) {
    half2v p; p.x = (half_t)es[2 * k]; p.y = (half_t)es[2 * k + 1];
    e_h2[(size_t)lb * 64 + k] = p;
  }
  float u = 0.f, v = ba0[k];
  #pragma unroll 8
  for (int d = 0; d < EE; ++d) {
    float x = es[d];
    u += (float)Wa0Ta[d * EE + k] * x;
    v += (float)Wa0Tb[d * EE + k] * x;
  }
  U[(size_t)lb * EE + k] = u;
  V[(size_t)lb * EE + k] = v;
}

// ---------------------------------------------------------------------------
// w_pre[i,b,h] = sum_j sum_k Wa1[h,k] * relu(U[j,b,k]+V[i,b,k]) + L*ba1[h]
// ---------------------------------------------------------------------------
__global__ __launch_bounds__(128) void attn_w_kernel(
    const float* __restrict__ U, const float* __restrict__ V,
    const float* __restrict__ Wa1,  // [8][128]
    const float* __restrict__ ba1,  // [8]
    float* __restrict__ wpre)       // [L][B][8]
{
  int ig = blockIdx.x >> 5;
  int b = blockIdx.x & 31;
  int i0 = ig * 4;
  int k = threadIdx.x;  // 128
  float vk[4];
  #pragma unroll
  for (int ii = 0; ii < 4; ++ii) vk[ii] = V[((size_t)(i0 + ii) * BB + b) * EE + k];
  float wa[NHH], acc[4][NHH];
  #pragma unroll
  for (int h = 0; h < NHH; ++h) wa[h] = Wa1[h * EE + k];
  #pragma unroll
  for (int ii = 0; ii < 4; ++ii)
    #pragma unroll
    for (int h = 0; h < NHH; ++h) acc[ii][h] = 0.f;
  for (int j = 0; j < LL; ++j) {
    float u = U[((size_t)j * BB + b) * EE + k];
    #pragma unroll
    for (int ii = 0; ii < 4; ++ii) {
      float tv = fmaxf(u + vk[ii], 0.f);
      #pragma unroll
      for (int h = 0; h < NHH; ++h) acc[ii][h] += wa[h] * tv;
    }
  }
  __shared__ float part[2][32];
  int wave = k >> 6, lane = k & 63;
  #pragma unroll
  for (int ii = 0; ii < 4; ++ii)
    #pragma unroll
    for (int h = 0; h < NHH; ++h) {
      float a = acc[ii][h];
      #pragma unroll
      for (int off = 32; off > 0; off >>= 1) a += __shfl_xor(a, off, 64);
      if (lane == 0) part[wave][ii * 8 + h] = a;
    }
  __syncthreads();
  if (k < 32) {
    int ii = k >> 3, h = k & 7;
    float w = part[0][k] + part[1][k] + (float)LL * ba1[h];
    wpre[((size_t)(i0 + ii) * BB + b) * NHH + h] = w;
  }
}

// softmax over l of (w * mask): masked entries become 0 and STAY in the softmax
__global__ void attn_softmax_kernel(
    const float* __restrict__ wpre, const int* __restrict__ slen,
    float* __restrict__ wsoft)
{
  int b = blockIdx.x >> 3;
  int h = blockIdx.x & 7;
  int l = threadIdx.x;  // 128
  int len = slen[b];
  float x = wpre[((size_t)l * BB + b) * NHH + h];
  float xv = (l < len) ? x : 0.f;
  float m = xv;
  #pragma unroll
  for (int off = 32; off > 0; off >>= 1) m = fmaxf(m, __shfl_xor(m, off, 64));
  __shared__ float sm[2], ss[2];
  int wave = l >> 6;
  if ((l & 63) == 0) sm[wave] = m;
  __syncthreads();
  m = fmaxf(sm[0], sm[1]);
  float e = __expf(xv - m);
  float s = e;
  #pragma unroll
  for (int off = 32; off > 0; off >>= 1) s += __shfl_xor(s, off, 64);
  if ((l & 63) == 0) ss[wave] = s;
  __syncthreads();
  s = ss[0] + ss[1];
  wsoft[((size_t)l * BB + b) * NHH + h] = e / s;
}

// ---------------------------------------------------------------------------
// gi0: [e, ts] @ Wih0.T + bih0, 8 lb per block, v_dot2 on packed pairs
// ---------------------------------------------------------------------------
__global__ __launch_bounds__(256) void gi0_kernel(
    const half2v* __restrict__ e_h2, const float* __restrict__ ts,
    const half2v* __restrict__ W2,   // [65][768]
    const float* __restrict__ bih,
    float* __restrict__ gi)
{
  int lb0 = blockIdx.x * 8;
  int tid = threadIdx.x;  // 256
  __shared__ half2v xs2[8][66];
  for (int idx = tid; idx < 512; idx += 256) {
    int q = idx >> 6, d2 = idx & 63;
    xs2[q][d2] = e_h2[(size_t)(lb0 + q) * 64 + d2];
  }
  if (tid < 8) {
    half2v t2; t2.x = (half_t)ts[(lb0 + tid) * 2]; t2.y = (half_t)ts[(lb0 + tid) * 2 + 1];
    xs2[tid][64] = t2;
  }
  __syncthreads();
  float acc[8][3];
  #pragma unroll
  for (int q = 0; q < 8; ++q) { acc[q][0] = 0.f; acc[q][1] = 0.f; acc[q][2] = 0.f; }
  for (int d2 = 0; d2 < 65; ++d2) {
    half2v w0 = W2[d2 * 768 + tid];
    half2v w1 = W2[d2 * 768 + 256 + tid];
    half2v w2 = W2[d2 * 768 + 512 + tid];
    #pragma unroll
    for (int q = 0; q < 8; ++q) {
      half2v x = xs2[q][d2];
      acc[q][0] = fdot2f(w0, x, acc[q][0]);
      acc[q][1] = fdot2f(w1, x, acc[q][1]);
      acc[q][2] = fdot2f(w2, x, acc[q][2]);
    }
  }
  float b0 = bih[tid], b1 = bih[256 + tid], b2 = bih[512 + tid];
  #pragma unroll
  for (int q = 0; q < 8; ++q) {
    float* gp = gi + (size_t)(lb0 + q) * G3;
    gp[tid] = acc[q][0] + b0; gp[256 + tid] = acc[q][1] + b1; gp[512 + tid] = acc[q][2] + b2;
  }
}

// ---------------------------------------------------------------------------
// gi1: out0 @ Wih1.T + bih1, 8 lb per block
// ---------------------------------------------------------------------------
__global__ __launch_bounds__(256) void gi1_kernel(
    const float* __restrict__ out0,  // [L*B][256]
    const half2v* __restrict__ W2,   // [128][768]
    const float* __restrict__ bih,
    float* __restrict__ gi)
{
  int lb0 = blockIdx.x * 8;
  int tid = threadIdx.x;  // 256
  __shared__ half2v xs2[8][128];
  for (int idx = tid; idx < 1024; idx += 256) {
    int q = idx >> 7, d2 = idx & 127;
    float2 v = ((const float2*)(out0 + (size_t)(lb0 + q) * HH))[d2];
    half2v x; x.x = (half_t)v.x; x.y = (half_t)v.y;
    xs2[q][d2] = x;
  }
  __syncthreads();
  float acc[8][3];
  #pragma unroll
  for (int q = 0; q < 8; ++q) { acc[q][0] = 0.f; acc[q][1] = 0.f; acc[q][2] = 0.f; }
  for (int d2 = 0; d2 < 128; ++d2) {
    half2v w0 = W2[d2 * 768 + tid];
    half2v w1 = W2[d2 * 768 + 256 + tid];
    half2v w2 = W2[d2 * 768 + 512 + tid];
    #pragma unroll
    for (int q = 0; q < 8; ++q) {
      half2v x = xs2[q][d2];
      acc[q][0] = fdot2f(w0, x, acc[q][0]);
      acc[q][1] = fdot2f(w1, x, acc[q][1]);
      acc[q][2] = fdot2f(w2, x, acc[q][2]);
    }
  }
  float b0 = bih[tid], b1 = bih[256 + tid], b2 = bih[512 + tid];
  #pragma unroll
  for (int q = 0; q < 8; ++q) {
    float* gp = gi + (size_t)(lb0 + q) * G3;
    gp[tid] = acc[q][0] + b0; gp[256 + tid] = acc[q][1] + b1; gp[512 + tid] = acc[q][2] + b2;
  }
}

// ---------------------------------------------------------------------------
// GRU scan, STREAMING fp8-MFMA, 8 waves. r9's 4-wave version was latency-
// bound (3540 cyc/step vs the 1465-cyc L2-BW floor) and spilled (VGPR=152
// vs 192 asked). Fix both: 512 threads = 8 waves (2/SIMD), each wave owns
// 32 h-indices x 3 gates = 6 tiles in 3 pipelined groups of 2 tiles
// (16 uint2 in flight per group, <=64 weight regs live + 16 ha + 24 acc
// ~= 150 regs, no spill at the 256 cap). 2x waves => 2x outstanding-load
// coverage => approach the L2-BW floor like r5 did for f16.
// Fragment layout byte-identical to r8 (absmax 0.031 verified).
// ---------------------------------------------------------------------------
__global__ __launch_bounds__(512, 2) void gru_scan_kernel(
    const __hip_fp8_e4m3* __restrict__ Whhq, // [768][256] fp8
    const float* __restrict__ bhh,           // [768]
    const float* __restrict__ gi,            // [L][B][768]
    const int* __restrict__ slen,            // [B]
    float* __restrict__ out,                 // [L][B][256]
    float* __restrict__ hT)                  // [B][256]
{
  const int b = blockIdx.x;
  const int tid = threadIdx.x;  // 512
  const int w = tid >> 6;       // 8 waves
  const int lane = tid & 63;
  const int col = lane & 15;
  const int quad = lane >> 4;
  __shared__ __align__(8) unsigned char hs[2][HH];  // double-buffered fp8 h

  const unsigned char* Wq = (const unsigned char*)Whhq;
  // tile (g,tau): row = 256*g + 32*w + 16*tau + col; byte = row*256 + 32*ks + 8*quad
  const unsigned char* base = Wq + (size_t)(32 * w + col) * HH + 8 * quad;

  uint2 wbuf[3][16];  // 3 groups (one per gate) x 2 tiles x 8 ks
#define LOADG(g)                                                            \
  {                                                                         \
    _Pragma("unroll")                                                       \
    for (int i = 0; i < 16; ++i)                                            \
      wbuf[g][i] = *(const uint2*)(base + (g) * 65536 + (i >> 3) * 4096 +   \
                                   (i & 7) * 32);                           \
  }
#define MFMAG(g)                                                            \
  {                                                                         \
    _Pragma("unroll")                                                       \
    for (int ks = 0; ks < 8; ++ks) {                                        \
      _Pragma("unroll")                                                     \
      for (int tau = 0; tau < 2; ++tau)                                     \
        acc[(g) * 2 + tau] = __builtin_amdgcn_mfma_f32_16x16x32_fp8_fp8(    \
            ha[ks], __builtin_bit_cast(long, wbuf[g][tau * 8 + ks]),        \
            acc[(g) * 2 + tau], 0, 0, 0);                                   \
    }                                                                       \
  }

  const int len = slen[b];
  const int mytau = (lane >> 4) & 1;
  const int j = 32 * w + 16 * mytau + col;  // this lane's h-index (lane<32)
  const bool owner = lane < 32;
  float hold = 0.f, br = 0.f, bz = 0.f, bn = 0.f;
  if (owner) { br = bhh[j]; bz = bhh[HH + j]; bn = bhh[2 * HH + j]; }
  if (tid < 128) ((unsigned int*)hs)[tid] = 0u;  // zero both buffers
  __syncthreads();

  const float* gib = gi + (size_t)b * G3;
  float* outb = out + (size_t)b * HH;

  LOADG(0)  // prologue

  #pragma unroll 1
  for (int t = 0; t < LL; ++t) {
    const unsigned char* hr = hs[t & 1];
    unsigned char* hw = (unsigned char*)hs[(t & 1) ^ 1];
    LOADG(1)
    const float* gp = gib + (size_t)t * (BB * G3);
    float c0 = 0.f, c1 = 0.f, c2 = 0.f;
    if (owner) { c0 = gp[j]; c1 = gp[HH + j]; c2 = gp[2 * HH + j]; }
    // h fragments from LDS (8B each, A-operand replicated over M)
    long ha[8];
    #pragma unroll
    for (int ks = 0; ks < 8; ++ks)
      ha[ks] = __builtin_bit_cast(long, *(const uint2*)(hr + 32 * ks + 8 * quad));
    floatx4 acc[6];
    #pragma unroll
    for (int i = 0; i < 6; ++i) { floatx4 z = {0.f, 0.f, 0.f, 0.f}; acc[i] = z; }
    MFMAG(0)
    LOADG(2)
    MFMAG(1)
    LOADG(0)  // prefetch next step's group 0 — stays in flight across barrier
    MFMAG(2)
    bool valid = t < len;
    if (owner) {
      float r_ = sigmoidf_(c0 + acc[mytau].x + br);
      float z_ = sigmoidf_(c1 + acc[2 + mytau].x + bz);
      float n_ = tanhf_(c2 + r_ * (acc[4 + mytau].x + bn));
      float hnew = (1.f - z_) * n_ + z_ * hold;
      hold = valid ? hnew : hold;
      ((__hip_fp8_e4m3*)hw)[j] = __hip_fp8_e4m3(hold);
      outb[(size_t)t * (BB * HH) + j] = valid ? hnew : 0.f;
    }
    BARRIER_LDS();  // single barrier: writes went to the other h buffer
  }
  if (owner) hT[(size_t)b * HH + j] = hold;
#undef LOADG
#undef MFMAG
}

// ---------------------------------------------------------------------------
// fused ctx + final MLP: ctx[h,d] = sum_l wsoft[l,b,h]*out1[l,b,d];
// z = selu([ctx,hT]@Wf0.T+bf0); logits = z@Wf1.T+bf1; out = log_softmax.
// ---------------------------------------------------------------------------
__global__ __launch_bounds__(512) void final_kernel(
    const float* __restrict__ wsoft,  // [L][B][8]
    const float* __restrict__ out1,   // [L][B][256]
    const float* __restrict__ hT,
    const float* __restrict__ Wf0,    // [168][2304]
    const float* __restrict__ bf0,
    const float* __restrict__ Wf1,    // [100][168]
    const float* __restrict__ bf1,
    float* __restrict__ outp)         // [B][100]
{
  int b = blockIdx.x;
  int tid = threadIdx.x;
  int wave = tid >> 6, lane = tid & 63;
  __shared__ float4 xs4[CLSIN / 4];
  __shared__ float ws[LL][NHH];
  __shared__ float part[NHH * HH];
  __shared__ float zs[F1];
  __shared__ float ls[ETA];
  float* xs = (float*)xs4;
  for (int i = tid; i < LL * NHH; i += 512) {
    int l = i >> 3, h = i & 7;
    ws[l][h] = wsoft[((size_t)l * BB + b) * NHH + h];
  }
  if (tid < HH) xs[NHH * HH + tid] = hT[(size_t)b * HH + tid];
  __syncthreads();
  {
    int d = tid & 255, lh = tid >> 8;
    float ac[NHH] = {0.f, 0.f, 0.f, 0.f, 0.f, 0.f, 0.f, 0.f};
    for (int l = 64 * lh; l < 64 * (lh + 1); ++l) {
      float x = out1[((size_t)l * BB + b) * HH + d];
      #pragma unroll
      for (int h = 0; h < NHH; ++h) ac[h] += ws[l][h] * x;
    }
    if (lh) {
      #pragma unroll
      for (int h = 0; h < NHH; ++h) part[h * HH + d] = ac[h];
    }
    __syncthreads();
    if (!lh) {
      #pragma unroll
      for (int h = 0; h < NHH; ++h) xs[h * HH + d] = ac[h] + part[h * HH + d];
    }
    __syncthreads();
  }
  for (int r = wave; r < F1; r += 8) {
    const float4* wp = (const float4*)(Wf0 + (size_t)r * CLSIN);
    float acc = 0.f;
    #pragma unroll
    for (int i = 0; i < CLSIN / 4 / 64; ++i) {  // 9
      float4 w = wp[lane + 64 * i];
      float4 x = xs4[lane + 64 * i];
      acc += w.x * x.x + w.y * x.y + w.z * x.z + w.w * x.w;
    }
    #pragma unroll
    for (int off = 32; off > 0; off >>= 1) acc += __shfl_xor(acc, off, 64);
    if (lane == 0) {
      float x = acc + bf0[r];
      const float alpha = 1.6732632423543772f, scale = 1.0507009873554805f;
      zs[r] = scale * (x > 0.f ? x : alpha * (__expf(x) - 1.f));
    }
  }
  __syncthreads();
  for (int r = wave; r < ETA; r += 8) {
    float acc = 0.f;
    for (int k = lane; k < F1; k += 64) acc += Wf1[r * F1 + k] * zs[k];
    #pragma unroll
    for (int off = 32; off > 0; off >>= 1) acc += __shfl_xor(acc, off, 64);
    if (lane == 0) ls[r] = acc + bf1[r];
  }
  __syncthreads();
  if (wave == 0) {
    float v0 = (lane < ETA) ? ls[lane] : -1e30f;
    float v1 = (lane + 64 < ETA) ? ls[lane + 64] : -1e30f;
    float m = fmaxf(v0, v1);
    #pragma unroll
    for (int off = 32; off > 0; off >>= 1) m = fmaxf(m, __shfl_xor(m, off, 64));
    float s = __expf(v0 - m) + __expf(v1 - m);
    #pragma unroll
    for (int off = 32; off > 0; off >>= 1) s += __shfl_xor(s, off, 64);
    float lse = m + __logf(s);
    if (lane < ETA) outp[(size_t)b * ETA + lane] = v0 - lse;
    if (lane + 64 < ETA) outp[(size_t)b * ETA + lane + 64] = v1 - lse;
  }
}

extern "C" void kernel_launch(void* const* d_in, const int* in_sizes, int n_in,
                              void* d_out, int out_size, void* d_ws, size_t ws_size,
                              hipStream_t stream) {
  const int*   node  = (const int*)d_in[0];
  const float* ts    = (const float*)d_in[1];
  const int*   slen  = (const int*)d_in[2];
  const float* table = (const float*)d_in[3];
  const float* Wih0  = (const float*)d_in[4];
  const float* Whh0  = (const float*)d_in[5];
  const float* bih0  = (const float*)d_in[6];
  const float* bhh0  = (const float*)d_in[7];
  const float* Wih1  = (const float*)d_in[8];
  const float* Whh1  = (const float*)d_in[9];
  const float* bih1  = (const float*)d_in[10];
  const float* bhh1  = (const float*)d_in[11];
  const float* Wa0   = (const float*)d_in[12];
  const float* ba0   = (const float*)d_in[13];
  const float* Wa1   = (const float*)d_in[14];
  const float* ba1   = (const float*)d_in[15];
  const float* Wf0   = (const float*)d_in[16];
  const float* bf0   = (const float*)d_in[17];
  const float* Wf1   = (const float*)d_in[18];
  const float* bf1   = (const float*)d_in[19];

  char* ws = (char*)d_ws;
  size_t off = 0;
  auto alloc = [&](size_t n) { void* p = (void*)(ws + off); off += (n + 255) & ~(size_t)255; return p; };

  half2v* e_h2 = (half2v*)alloc((size_t)LL * BB * 64 * 4);
  float* U     = (float*)alloc((size_t)LL * BB * EE * 4);
  float* V     = (float*)alloc((size_t)LL * BB * EE * 4);
  float* gi    = (float*)alloc((size_t)LL * BB * G3 * 4);   // reused for both layers
  float* out0  = (float*)alloc((size_t)LL * BB * HH * 4);
  float* out1  = (float*)alloc((size_t)LL * BB * HH * 4);
  float* hTb   = (float*)alloc((size_t)BB * HH * 4);
  float* wpre  = (float*)alloc((size_t)LL * BB * NHH * 4);
  float* wsoft = (float*)alloc((size_t)LL * BB * NHH * 4);
  half_t* Wa0Ta = (half_t*)alloc((size_t)128 * 128 * 2);
  half_t* Wa0Tb = (half_t*)alloc((size_t)128 * 128 * 2);
  half2v* Wih0T2 = (half2v*)alloc((size_t)65 * 768 * 4);
  half2v* Wih1T2 = (half2v*)alloc((size_t)128 * 768 * 4);
  __hip_fp8_e4m3* Whh0q = (__hip_fp8_e4m3*)alloc((size_t)G3 * HH);
  __hip_fp8_e4m3* Whh1q = (__hip_fp8_e4m3*)alloc((size_t)G3 * HH);
  if (off > ws_size) return;  // workspace too small: fail visibly

  const int prep_total = 16384 + 16384 + 65 * 768 + 128 * 768 + 196608 + 196608;
  prep_kernel<<<(prep_total + 255) / 256, 256, 0, stream>>>(
      Wa0, Wih0, Wih1, Whh0, Whh1, Wa0Ta, Wa0Tb, Wih0T2, Wih1T2, Whh0q, Whh1q);
  embed_uv_kernel<<<LL * BB, 128, 0, stream>>>(node, table, Wa0Ta, Wa0Tb, ba0, e_h2, U, V);
  attn_w_kernel<<<(LL / 4) * BB, 128, 0, stream>>>(U, V, Wa1, ba1, wpre);
  attn_softmax_kernel<<<BB * NHH, 128, 0, stream>>>(wpre, slen, wsoft);
  gi0_kernel<<<LL * BB / 8, 256, 0, stream>>>(e_h2, ts, Wih0T2, bih0, gi);
  gru_scan_kernel<<<BB, 512, 0, stream>>>(Whh0q, bhh0, gi, slen, out0, hTb);
  gi1_kernel<<<LL * BB / 8, 256, 0, stream>>>(out0, Wih1T2, bih1, gi);
  gru_scan_kernel<<<BB, 512, 0, stream>>>(Whh1q, bhh1, gi, slen, out1, hTb);
  final_kernel<<<BB, 512, 0, stream>>>(wsoft, out1, hTb, Wf0, bf0, Wf1, bf1, (float*)d_out);
}